// Round 1
// baseline (1526.603 us; speedup 1.0000x reference)
//
#include <hip/hip_runtime.h>

// ---------------------------------------------------------------------------
// VectorQuantizer, np-fp32-faithful argmin. Round 6 = round 5 + NT A-staging:
//   THEORY: FETCH_SIZE 2.08 GB == per-block compulsory traffic -> zero L2
//   reuse of the 1 MB B-chunk that is pinned per-XCD (by = blk&7 == XCD id).
//   The A stream (32 MB/XCD, zero in-XCD reuse) turns the 4 MB L2 over every
//   ~10us and evicts B. Fix: A staging loads carry CPol nt (aux bit1) so A is
//   evict-first and B stays L2-resident. B loads remain default-cached.
//   - XOR swizzle on LDS K-chunks (slot = chunk ^ (row&7)), source-permuted
//     staging since global_load_lds scatters base + lane*16
//   - grid 2048: 4 blocks/CU (LDS 34816B-capped)
//   - cvt+norm fused; rescore = OpenBLAS fp32 chain (kc=384 split) [round-3
//     validated, absmax 0]
// Scratch inside d_out quantized region (overwritten by writeout_k):
//   [0) zb 32MB][32M) eb 8MB][40M) b32 32KB][+32K) a32 128KB]
//   [+128K) candk 8MB][+8M) candi 8MB]   (ends ~58.9MB < 64MB)
// d_ws: 8 bytes (loss accumulator).
// ---------------------------------------------------------------------------

#define N_ROWS 32768
#define K_CODES 8192
#define DIM 512

typedef __attribute__((ext_vector_type(8))) short short8;
typedef __attribute__((ext_vector_type(4))) float f32x4;

#define MARGIN 5e-4f

__device__ __forceinline__ unsigned short f2bf(float f) {
  unsigned int u = __float_as_uint(f);
  u = u + 0x7fffu + ((u >> 16) & 1u);   // round-to-nearest-even
  return (unsigned short)(u >> 16);
}

__device__ __forceinline__ double shfl_xor_dbl(double v, int m) {
  union { double d; int i[2]; } u;
  u.d = v;
  u.i[0] = __shfl_xor(u.i[0], m, 64);
  u.i[1] = __shfl_xor(u.i[1], m, 64);
  return u.d;
}

// opaque: block fp contraction across this value (keep separate RN32 steps)
__device__ __forceinline__ float opaque_f(float x) {
  asm volatile("" : "+v"(x));
  return x;
}

// ------- 1) fused fp32 -> bf16 + row squared-norm (one wave per row) -------
__global__ __launch_bounds__(256) void cvtnorm_k(const float* __restrict__ in,
                                                 unsigned short* __restrict__ outb,
                                                 float* __restrict__ outn) {
  const int r = blockIdx.x * 4 + (threadIdx.x >> 6);
  const int lane = threadIdx.x & 63;
  const float* xr = in + (size_t)r * DIM + lane * 8;
  const float4 a = *(const float4*)xr;
  const float4 b = *(const float4*)(xr + 4);
  uint4 o;
  o.x = (unsigned)f2bf(a.x) | ((unsigned)f2bf(a.y) << 16);
  o.y = (unsigned)f2bf(a.z) | ((unsigned)f2bf(a.w) << 16);
  o.z = (unsigned)f2bf(b.x) | ((unsigned)f2bf(b.y) << 16);
  o.w = (unsigned)f2bf(b.z) | ((unsigned)f2bf(b.w) << 16);
  *(uint4*)(outb + (size_t)r * DIM + lane * 8) = o;
  double s = (double)a.x * a.x + (double)a.y * a.y + (double)a.z * a.z + (double)a.w * a.w
           + (double)b.x * b.x + (double)b.y * b.y + (double)b.z * b.z + (double)b.w * b.w;
#pragma unroll
  for (int m = 1; m < 64; m <<= 1) s += shfl_xor_dbl(s, m);
  if (lane == 0) outn[r] = (float)s;
}

// ---------------- 2) bf16 GEMM + fused streamed top-4 ----------------------
// grid 2048: bx=blk>>3 -> 128 z-rows; by=blk&7 -> 1024-code chunk (ct<8).
// Block 256 = 4 waves 2x2; wave tile 64x64 = 4x4 MFMA 16x16x32.
// LDS bank-conflict fix: K-chunk c (16B) of row r lives at slot (c ^ (r&7)).
// Cache policy: A staged with CPol nt (aux=2) -> evict-first in L2; the
// per-XCD 1 MB B-chunk stays resident and its 256x re-reads become L2 hits.
__global__ __launch_bounds__(256, 4) void gemm_topk(
    const unsigned short* __restrict__ A,   // z bf16 [32768][512]
    const unsigned short* __restrict__ B,   // e bf16 [8192][512]
    const float* __restrict__ en2,          // [8192] = b32
    float* __restrict__ candk,              // [32768][64]
    int* __restrict__ candi)                // [32768][64]
{
  __shared__ char lds[34816];
  float* scorebuf = (float*)lds;                 // [128][67], aliases staging
  float* e2s = (float*)(lds + 34304);            // [128]

  const int tid = threadIdx.x;
  const int lane = tid & 63, wave = tid >> 6;
  const int wm = wave >> 1, wn = wave & 1;
  const int quad = lane >> 4, lcol = lane & 15;
  const int bx = blockIdx.x >> 3, by = blockIdx.x & 7;
  const int row0 = bx * 128;
  const int cstart = by * 1024;                  // FULL coverage: 8 x 1024
  const int hf = tid & 1, srow = tid >> 1;       // scan ownership

  float tk0 = 3.4e38f, tk1 = 3.4e38f, tk2 = 3.4e38f, tk3 = 3.4e38f;
  int ti0 = 0, ti1 = 0, ti2 = 0, ti3 = 0;

  // staging: lane -> (local row, swizzled source chunk)
  const int srw = lane >> 3;                     // 0..7
  const int sch = (lane & 7) ^ srw;              // source K-chunk (16B units)
  const unsigned short* Ag =
      A + ((size_t)(row0 + wave * 32 + srw)) * DIM + sch * 8;
  const int ldsA = wave * 4096;
  const int ldsB = 16384 + wave * 4096;

  // fragment readers: row byte base + swizzled chunk offset
  const int xr = lcol & 7;
  int abase[4], bbase[4];
#pragma unroll
  for (int i = 0; i < 4; ++i) abase[i] = (wm * 64 + i * 16 + lcol) * 128;
#pragma unroll
  for (int j = 0; j < 4; ++j) bbase[j] = 16384 + (wn * 64 + j * 16 + lcol) * 128;
  int coff[2];
#pragma unroll
  for (int kk = 0; kk < 2; ++kk) coff[kk] = ((kk * 4 + quad) ^ xr) * 16;

#pragma unroll 1
  for (int ct = 0; ct < 8; ++ct) {
    const int c0 = cstart + ct * 128;
    if (tid < 128) e2s[tid] = en2[c0 + tid];
    const unsigned short* Bg =
        B + ((size_t)(c0 + wave * 32 + srw)) * DIM + sch * 8;

    f32x4 acc[4][4];
#pragma unroll
    for (int i = 0; i < 4; ++i)
#pragma unroll
      for (int j = 0; j < 4; ++j) acc[i][j] = 0.f;

#pragma unroll
    for (int kt = 0; kt < 8; ++kt) {
      const int k0 = kt * 64;
      __syncthreads();
#pragma unroll
      for (int j = 0; j < 4; ++j) {
        // A: nt (aux=2) — stream past L2, don't evict the resident B-chunk
        __builtin_amdgcn_global_load_lds(
            (const __attribute__((address_space(1))) void*)(uintptr_t)(Ag + k0 + j * (8 * DIM)),
            (__attribute__((address_space(3))) void*)(uintptr_t)(lds + ldsA + j * 1024),
            16, 0, 2);
        // B: default policy — cached, L2-resident per XCD
        __builtin_amdgcn_global_load_lds(
            (const __attribute__((address_space(1))) void*)(uintptr_t)(Bg + k0 + j * (8 * DIM)),
            (__attribute__((address_space(3))) void*)(uintptr_t)(lds + ldsB + j * 1024),
            16, 0, 0);
      }
      __syncthreads();
#pragma unroll
      for (int kk = 0; kk < 2; ++kk) {
        short8 af[4], bfr[4];
#pragma unroll
        for (int i = 0; i < 4; ++i) af[i] = *(const short8*)(lds + abase[i] + coff[kk]);
#pragma unroll
        for (int j = 0; j < 4; ++j) bfr[j] = *(const short8*)(lds + bbase[j] + coff[kk]);
#pragma unroll
        for (int i = 0; i < 4; ++i)
#pragma unroll
          for (int j = 0; j < 4; ++j)
            acc[i][j] = __builtin_amdgcn_mfma_f32_16x16x32_bf16(af[i], bfr[j], acc[i][j], 0, 0, 0);
      }
    }

#pragma unroll 1
    for (int h = 0; h < 2; ++h) {
      __syncthreads();
      if (wn == h) {
#pragma unroll
        for (int i = 0; i < 4; ++i)
#pragma unroll
          for (int j = 0; j < 4; ++j) {
            const float eb2 = e2s[64 * h + 16 * j + lcol];
#pragma unroll
            for (int r = 0; r < 4; ++r)
              scorebuf[(wm * 64 + i * 16 + quad * 4 + r) * 67 + 16 * j + lcol] =
                  fmaf(acc[i][j][r], -2.0f, eb2);
          }
      }
      __syncthreads();
      const float* sp = scorebuf + srow * 67 + hf * 32;
      const int idbase = c0 + 64 * h + 32 * hf;
#pragma unroll 8
      for (int cc = 0; cc < 32; ++cc) {
        const float key = sp[cc];
        if (key < tk3) {
          const int id = idbase + cc;
          if (key < tk2) {
            tk3 = tk2; ti3 = ti2;
            if (key < tk1) {
              tk2 = tk1; ti2 = ti1;
              if (key < tk0) { tk1 = tk0; ti1 = ti0; tk0 = key; ti0 = id; }
              else           { tk1 = key; ti1 = id; }
            } else { tk2 = key; ti2 = id; }
          } else { tk3 = key; ti3 = id; }
        }
      }
    }
  }

  const size_t cb = ((size_t)(row0 + srow)) * 64 + by * 8 + hf * 4;
  candk[cb + 0] = tk0; candk[cb + 1] = tk1; candk[cb + 2] = tk2; candk[cb + 3] = tk3;
  candi[cb + 0] = ti0; candi[cb + 1] = ti1; candi[cb + 2] = ti2; candi[cb + 3] = ti3;
}

// ---------------- 3) np-faithful fp32 rescore ------------------------------
// OpenBLAS sgemm model: m32 = RN32(chain(0..383) + chain(384..511)),
// each chain a sequential fp32 fma; then d = RN32(RN32(a+b) - RN32(2*m)).
__global__ __launch_bounds__(256) void rescore_np(
    const float* __restrict__ z, const float* __restrict__ e,
    const float* __restrict__ a32, const float* __restrict__ b32,
    const float* __restrict__ candk, const int* __restrict__ candi,
    float* __restrict__ idxout)
{
  const int row = blockIdx.x * 256 + threadIdx.x;

  const float* ckr = candk + (size_t)row * 64;
  const int* cir = candi + (size_t)row * 64;
  float kmin = 3.4e38f;
#pragma unroll 8
  for (int j = 0; j < 64; ++j) kmin = fminf(kmin, ckr[j]);
  const float cut = kmin + MARGIN;

  const float a = a32[row];
  const float* zr = z + (size_t)row * DIM;

  float bd = 3.4e38f;
  int bc = 0x7fffffff;
#pragma unroll 1
  for (int j = 0; j < 64; ++j) {
    if (ckr[j] <= cut) {
      const int c = cir[j];
      const float* er = e + (size_t)c * DIM;
      // panel A: k = 0..383, sequential fp32 fma chain
      float s = 0.0f;
#pragma unroll 4
      for (int k4 = 0; k4 < 96; ++k4) {
        const float4 zv = *(const float4*)(zr + k4 * 4);
        const float4 ev = *(const float4*)(er + k4 * 4);
        s = fmaf(zv.x, ev.x, s);
        s = fmaf(zv.y, ev.y, s);
        s = fmaf(zv.z, ev.z, s);
        s = fmaf(zv.w, ev.w, s);
      }
      const float cA = s;
      // panel B: k = 384..511
      s = 0.0f;
#pragma unroll 4
      for (int k4 = 96; k4 < 128; ++k4) {
        const float4 zv = *(const float4*)(zr + k4 * 4);
        const float4 ev = *(const float4*)(er + k4 * 4);
        s = fmaf(zv.x, ev.x, s);
        s = fmaf(zv.y, ev.y, s);
        s = fmaf(zv.z, ev.z, s);
        s = fmaf(zv.w, ev.w, s);
      }
      const float m = cA + s;                    // RN32 panel combine
      const float t1 = a + b32[c];               // RN32(a + b_c)
      const float t2 = opaque_f(2.0f * m);       // RN32(2*m), no contraction
      const float d = t1 - t2;                   // RN32(t1 - t2)
      if (d < bd || (d == bd && c < bc)) { bd = d; bc = c; }
    }
  }
  idxout[row] = (float)bc;
}

// ---------------- 4) gather + straight-through output + loss ---------------
__global__ __launch_bounds__(256) void writeout_k(
    const float* __restrict__ z, const float* __restrict__ e,
    const float* __restrict__ idxf, float* __restrict__ outq,
    double* __restrict__ accum)
{
  const int tid = threadIdx.x;
  const size_t gid = (size_t)blockIdx.x * 256 + tid;
  const int row = (int)(gid >> 7);
  const int dq = ((int)gid & 127) << 2;
  const int c = (int)idxf[row];
  const float4 q4 = *(const float4*)(e + (size_t)c * DIM + dq);
  const float4 z4 = *(const float4*)(z + (size_t)row * DIM + dq);
  const float tx = q4.x - z4.x, ty = q4.y - z4.y, tz = q4.z - z4.z, tw = q4.w - z4.w;
  float4 o;
  o.x = z4.x + tx; o.y = z4.y + ty; o.z = z4.z + tz; o.w = z4.w + tw;
  *(float4*)(outq + (size_t)row * DIM + dq) = o;

  double s = (double)tx * tx + (double)ty * ty + (double)tz * tz + (double)tw * tw;
#pragma unroll
  for (int m = 1; m < 64; m <<= 1) s += shfl_xor_dbl(s, m);
  __shared__ double wsum[4];
  if ((tid & 63) == 0) wsum[tid >> 6] = s;
  __syncthreads();
  if (tid == 0) atomicAdd(accum, wsum[0] + wsum[1] + wsum[2] + wsum[3]);
}

// ---------------- 5) finalize loss -----------------------------------------
__global__ void finalize_k(const double* __restrict__ accum, float* __restrict__ lossp) {
  *lossp = (float)(1.25 * accum[0] / (double)((size_t)N_ROWS * DIM));
}

// ---------------------------------------------------------------------------
extern "C" void kernel_launch(void* const* d_in, const int* in_sizes, int n_in,
                              void* d_out, int out_size, void* d_ws, size_t ws_size,
                              hipStream_t stream) {
  const float* z = (const float*)d_in[0];   // [32768*512] f32
  const float* e = (const float*)d_in[1];   // [8192*512]  f32
  float* out = (float*)d_out;
  char* ob = (char*)d_out;

  // scratch inside the 64MB quantized region (overwritten by writeout_k)
  unsigned short* zb = (unsigned short*)ob;                  // 33,554,432 B
  unsigned short* eb = (unsigned short*)(ob + 33554432);     //  8,388,608 B
  float* b32   = (float*)(ob + 41943040);                    //     32,768 B
  float* a32   = (float*)(ob + 41975808);                    //    131,072 B
  float* candk = (float*)(ob + 42106880);                    //  8,388,608 B
  int*   candi = (int*)(ob + 50495488);                      //  8,388,608 B

  float* lossp = out + 16777216;
  float* idxs  = out + 16777217;
  double* accum = (double*)d_ws;

  hipMemsetAsync(d_ws, 0, sizeof(double), stream);
  cvtnorm_k<<<8192, 256, 0, stream>>>(z, zb, a32);
  cvtnorm_k<<<2048, 256, 0, stream>>>(e, eb, b32);
  gemm_topk<<<2048, 256, 0, stream>>>(zb, eb, b32, candk, candi);
  rescore_np<<<128, 256, 0, stream>>>(z, e, a32, b32, candk, candi, idxs);
  writeout_k<<<16384, 256, 0, stream>>>(z, e, idxs, out, accum);
  finalize_k<<<1, 1, 0, stream>>>(accum, lossp);
}

// Round 2
// 1102.868 us; speedup vs baseline: 1.3842x; 1.3842x over previous
//
#include <hip/hip_runtime.h>

// ---------------------------------------------------------------------------
// VectorQuantizer, np-fp32-faithful argmin. Round 7:
//   - REVERT round-6 NT hint (877us vs 743us, FETCH unchanged -> theory wrong)
//   - THEORY: missing ~664us of total is serialization, not bandwidth:
//     (a) writeout_k: 16384 same-address fp64 atomicAdds ~= 650us serial.
//         Fix: 512-block grid-stride writeout -> 512 atomics.
//     (b) rescore_np: 128 blocks = 2 waves/CU, serial dependent-FMA chains.
//         Fix: wave-per-row, LANE-PER-CANDIDATE (64 chains in parallel),
//         per-candidate RN32 chain bit-identical, lexicographic (d,c) min.
//   GEMM kernel itself = round-5 structure (743us), untouched except aux=0.
// Scratch inside d_out quantized region (overwritten by writeout_k):
//   [0) zb 32MB][32M) eb 8MB][40M) b32 32KB][+32K) a32 128KB]
//   [+128K) candk 8MB][+8M) candi 8MB]   (ends ~58.9MB < 64MB)
// d_ws: 8 bytes (loss accumulator).
// ---------------------------------------------------------------------------

#define N_ROWS 32768
#define K_CODES 8192
#define DIM 512

typedef __attribute__((ext_vector_type(8))) short short8;
typedef __attribute__((ext_vector_type(4))) float f32x4;

#define MARGIN 5e-4f

__device__ __forceinline__ unsigned short f2bf(float f) {
  unsigned int u = __float_as_uint(f);
  u = u + 0x7fffu + ((u >> 16) & 1u);   // round-to-nearest-even
  return (unsigned short)(u >> 16);
}

__device__ __forceinline__ double shfl_xor_dbl(double v, int m) {
  union { double d; int i[2]; } u;
  u.d = v;
  u.i[0] = __shfl_xor(u.i[0], m, 64);
  u.i[1] = __shfl_xor(u.i[1], m, 64);
  return u.d;
}

// opaque: block fp contraction across this value (keep separate RN32 steps)
__device__ __forceinline__ float opaque_f(float x) {
  asm volatile("" : "+v"(x));
  return x;
}

// ------- 1) fused fp32 -> bf16 + row squared-norm (one wave per row) -------
__global__ __launch_bounds__(256) void cvtnorm_k(const float* __restrict__ in,
                                                 unsigned short* __restrict__ outb,
                                                 float* __restrict__ outn) {
  const int r = blockIdx.x * 4 + (threadIdx.x >> 6);
  const int lane = threadIdx.x & 63;
  const float* xr = in + (size_t)r * DIM + lane * 8;
  const float4 a = *(const float4*)xr;
  const float4 b = *(const float4*)(xr + 4);
  uint4 o;
  o.x = (unsigned)f2bf(a.x) | ((unsigned)f2bf(a.y) << 16);
  o.y = (unsigned)f2bf(a.z) | ((unsigned)f2bf(a.w) << 16);
  o.z = (unsigned)f2bf(b.x) | ((unsigned)f2bf(b.y) << 16);
  o.w = (unsigned)f2bf(b.z) | ((unsigned)f2bf(b.w) << 16);
  *(uint4*)(outb + (size_t)r * DIM + lane * 8) = o;
  double s = (double)a.x * a.x + (double)a.y * a.y + (double)a.z * a.z + (double)a.w * a.w
           + (double)b.x * b.x + (double)b.y * b.y + (double)b.z * b.z + (double)b.w * b.w;
#pragma unroll
  for (int m = 1; m < 64; m <<= 1) s += shfl_xor_dbl(s, m);
  if (lane == 0) outn[r] = (float)s;
}

// ---------------- 2) bf16 GEMM + fused streamed top-4 ----------------------
// grid 2048: bx=blk>>3 -> 128 z-rows; by=blk&7 -> 1024-code chunk (ct<8).
// Block 256 = 4 waves 2x2; wave tile 64x64 = 4x4 MFMA 16x16x32.
// LDS bank-conflict fix: K-chunk c (16B) of row r lives at slot (c ^ (r&7)).
__global__ __launch_bounds__(256, 4) void gemm_topk(
    const unsigned short* __restrict__ A,   // z bf16 [32768][512]
    const unsigned short* __restrict__ B,   // e bf16 [8192][512]
    const float* __restrict__ en2,          // [8192] = b32
    float* __restrict__ candk,              // [32768][64]
    int* __restrict__ candi)                // [32768][64]
{
  __shared__ char lds[34816];
  float* scorebuf = (float*)lds;                 // [128][67], aliases staging
  float* e2s = (float*)(lds + 34304);            // [128]

  const int tid = threadIdx.x;
  const int lane = tid & 63, wave = tid >> 6;
  const int wm = wave >> 1, wn = wave & 1;
  const int quad = lane >> 4, lcol = lane & 15;
  const int bx = blockIdx.x >> 3, by = blockIdx.x & 7;
  const int row0 = bx * 128;
  const int cstart = by * 1024;                  // FULL coverage: 8 x 1024
  const int hf = tid & 1, srow = tid >> 1;       // scan ownership

  float tk0 = 3.4e38f, tk1 = 3.4e38f, tk2 = 3.4e38f, tk3 = 3.4e38f;
  int ti0 = 0, ti1 = 0, ti2 = 0, ti3 = 0;

  // staging: lane -> (local row, swizzled source chunk)
  const int srw = lane >> 3;                     // 0..7
  const int sch = (lane & 7) ^ srw;              // source K-chunk (16B units)
  const unsigned short* Ag =
      A + ((size_t)(row0 + wave * 32 + srw)) * DIM + sch * 8;
  const int ldsA = wave * 4096;
  const int ldsB = 16384 + wave * 4096;

  // fragment readers: row byte base + swizzled chunk offset
  const int xr = lcol & 7;
  int abase[4], bbase[4];
#pragma unroll
  for (int i = 0; i < 4; ++i) abase[i] = (wm * 64 + i * 16 + lcol) * 128;
#pragma unroll
  for (int j = 0; j < 4; ++j) bbase[j] = 16384 + (wn * 64 + j * 16 + lcol) * 128;
  int coff[2];
#pragma unroll
  for (int kk = 0; kk < 2; ++kk) coff[kk] = ((kk * 4 + quad) ^ xr) * 16;

#pragma unroll 1
  for (int ct = 0; ct < 8; ++ct) {
    const int c0 = cstart + ct * 128;
    if (tid < 128) e2s[tid] = en2[c0 + tid];
    const unsigned short* Bg =
        B + ((size_t)(c0 + wave * 32 + srw)) * DIM + sch * 8;

    f32x4 acc[4][4];
#pragma unroll
    for (int i = 0; i < 4; ++i)
#pragma unroll
      for (int j = 0; j < 4; ++j) acc[i][j] = 0.f;

#pragma unroll
    for (int kt = 0; kt < 8; ++kt) {
      const int k0 = kt * 64;
      __syncthreads();
#pragma unroll
      for (int j = 0; j < 4; ++j) {
        __builtin_amdgcn_global_load_lds(
            (const __attribute__((address_space(1))) void*)(uintptr_t)(Ag + k0 + j * (8 * DIM)),
            (__attribute__((address_space(3))) void*)(uintptr_t)(lds + ldsA + j * 1024),
            16, 0, 0);
        __builtin_amdgcn_global_load_lds(
            (const __attribute__((address_space(1))) void*)(uintptr_t)(Bg + k0 + j * (8 * DIM)),
            (__attribute__((address_space(3))) void*)(uintptr_t)(lds + ldsB + j * 1024),
            16, 0, 0);
      }
      __syncthreads();
#pragma unroll
      for (int kk = 0; kk < 2; ++kk) {
        short8 af[4], bfr[4];
#pragma unroll
        for (int i = 0; i < 4; ++i) af[i] = *(const short8*)(lds + abase[i] + coff[kk]);
#pragma unroll
        for (int j = 0; j < 4; ++j) bfr[j] = *(const short8*)(lds + bbase[j] + coff[kk]);
#pragma unroll
        for (int i = 0; i < 4; ++i)
#pragma unroll
          for (int j = 0; j < 4; ++j)
            acc[i][j] = __builtin_amdgcn_mfma_f32_16x16x32_bf16(af[i], bfr[j], acc[i][j], 0, 0, 0);
      }
    }

#pragma unroll 1
    for (int h = 0; h < 2; ++h) {
      __syncthreads();
      if (wn == h) {
#pragma unroll
        for (int i = 0; i < 4; ++i)
#pragma unroll
          for (int j = 0; j < 4; ++j) {
            const float eb2 = e2s[64 * h + 16 * j + lcol];
#pragma unroll
            for (int r = 0; r < 4; ++r)
              scorebuf[(wm * 64 + i * 16 + quad * 4 + r) * 67 + 16 * j + lcol] =
                  fmaf(acc[i][j][r], -2.0f, eb2);
          }
      }
      __syncthreads();
      const float* sp = scorebuf + srow * 67 + hf * 32;
      const int idbase = c0 + 64 * h + 32 * hf;
#pragma unroll 8
      for (int cc = 0; cc < 32; ++cc) {
        const float key = sp[cc];
        if (key < tk3) {
          const int id = idbase + cc;
          if (key < tk2) {
            tk3 = tk2; ti3 = ti2;
            if (key < tk1) {
              tk2 = tk1; ti2 = ti1;
              if (key < tk0) { tk1 = tk0; ti1 = ti0; tk0 = key; ti0 = id; }
              else           { tk1 = key; ti1 = id; }
            } else { tk2 = key; ti2 = id; }
          } else { tk3 = key; ti3 = id; }
        }
      }
    }
  }

  const size_t cb = ((size_t)(row0 + srow)) * 64 + by * 8 + hf * 4;
  candk[cb + 0] = tk0; candk[cb + 1] = tk1; candk[cb + 2] = tk2; candk[cb + 3] = tk3;
  candi[cb + 0] = ti0; candi[cb + 1] = ti1; candi[cb + 2] = ti2; candi[cb + 3] = ti3;
}

// ---------------- 3) np-faithful fp32 rescore, wave-per-row ----------------
// One wave per row; LANE j owns candidate j (64 in parallel, was serial).
// Per-candidate arithmetic bit-identical to round-5: OpenBLAS sgemm model
// m32 = RN32(chain(0..383) + chain(384..511)), sequential fp32 fma chains;
// d = RN32(RN32(a+b) - RN32(2*m)). Winner = lexicographic min (d, c), which
// equals the old j-ascending scan with (d<bd || (d==bd && c<bc)).
__global__ __launch_bounds__(256) void rescore_np(
    const float* __restrict__ z, const float* __restrict__ e,
    const float* __restrict__ a32, const float* __restrict__ b32,
    const float* __restrict__ candk, const int* __restrict__ candi,
    float* __restrict__ idxout)
{
  const int row = blockIdx.x * 4 + (threadIdx.x >> 6);
  const int lane = threadIdx.x & 63;

  const float myk = candk[(size_t)row * 64 + lane];
  float kmin = myk;
#pragma unroll
  for (int m = 1; m < 64; m <<= 1) kmin = fminf(kmin, __shfl_xor(kmin, m, 64));
  const float cut = kmin + MARGIN;

  float bd = 3.4e38f;
  int bc = 0x7fffffff;
  if (myk <= cut) {
    const int c = candi[(size_t)row * 64 + lane];
    const float* zr = z + (size_t)row * DIM;
    const float* er = e + (size_t)c * DIM;
    // panel A: k = 0..383, sequential fp32 fma chain
    float s = 0.0f;
#pragma unroll 4
    for (int k4 = 0; k4 < 96; ++k4) {
      const float4 zv = *(const float4*)(zr + k4 * 4);
      const float4 ev = *(const float4*)(er + k4 * 4);
      s = fmaf(zv.x, ev.x, s);
      s = fmaf(zv.y, ev.y, s);
      s = fmaf(zv.z, ev.z, s);
      s = fmaf(zv.w, ev.w, s);
    }
    const float cA = s;
    // panel B: k = 384..511
    s = 0.0f;
#pragma unroll 4
    for (int k4 = 96; k4 < 128; ++k4) {
      const float4 zv = *(const float4*)(zr + k4 * 4);
      const float4 ev = *(const float4*)(er + k4 * 4);
      s = fmaf(zv.x, ev.x, s);
      s = fmaf(zv.y, ev.y, s);
      s = fmaf(zv.z, ev.z, s);
      s = fmaf(zv.w, ev.w, s);
    }
    const float m = cA + s;                    // RN32 panel combine
    const float t1 = a32[row] + b32[c];        // RN32(a + b_c)
    const float t2 = opaque_f(2.0f * m);       // RN32(2*m), no contraction
    bd = t1 - t2;                              // RN32(t1 - t2)
    bc = c;
  }
  // lexicographic (d, c) min across the wave
#pragma unroll
  for (int mm = 1; mm < 64; mm <<= 1) {
    const float od = __shfl_xor(bd, mm, 64);
    const int oc = __shfl_xor(bc, mm, 64);
    if (od < bd || (od == bd && oc < bc)) { bd = od; bc = oc; }
  }
  if (lane == 0) idxout[row] = (float)bc;
}

// ---------------- 4) gather + straight-through output + loss ---------------
// Grid-stride over 4,194,304 float4-chunks with 512 blocks: ONE fp64 atomic
// per block (512 total, was 16384 same-address atomics ~= 650us serialized).
__global__ __launch_bounds__(256) void writeout_k(
    const float* __restrict__ z, const float* __restrict__ e,
    const float* __restrict__ idxf, float* __restrict__ outq,
    double* __restrict__ accum)
{
  const int tid = threadIdx.x;
  double s = 0.0;
  size_t gid = (size_t)blockIdx.x * 256 + tid;
#pragma unroll 1
  for (int it = 0; it < 32; ++it, gid += 131072) {
    const int row = (int)(gid >> 7);
    const int dq = ((int)gid & 127) << 2;
    const int c = (int)idxf[row];
    const float4 q4 = *(const float4*)(e + (size_t)c * DIM + dq);
    const float4 z4 = *(const float4*)(z + (size_t)row * DIM + dq);
    const float tx = q4.x - z4.x, ty = q4.y - z4.y, tz = q4.z - z4.z, tw = q4.w - z4.w;
    float4 o;
    o.x = z4.x + tx; o.y = z4.y + ty; o.z = z4.z + tz; o.w = z4.w + tw;
    *(float4*)(outq + (size_t)row * DIM + dq) = o;
    s += (double)tx * tx + (double)ty * ty + (double)tz * tz + (double)tw * tw;
  }
#pragma unroll
  for (int m = 1; m < 64; m <<= 1) s += shfl_xor_dbl(s, m);
  __shared__ double wsum[4];
  if ((tid & 63) == 0) wsum[tid >> 6] = s;
  __syncthreads();
  if (tid == 0) atomicAdd(accum, wsum[0] + wsum[1] + wsum[2] + wsum[3]);
}

// ---------------- 5) finalize loss -----------------------------------------
__global__ void finalize_k(const double* __restrict__ accum, float* __restrict__ lossp) {
  *lossp = (float)(1.25 * accum[0] / (double)((size_t)N_ROWS * DIM));
}

// ---------------------------------------------------------------------------
extern "C" void kernel_launch(void* const* d_in, const int* in_sizes, int n_in,
                              void* d_out, int out_size, void* d_ws, size_t ws_size,
                              hipStream_t stream) {
  const float* z = (const float*)d_in[0];   // [32768*512] f32
  const float* e = (const float*)d_in[1];   // [8192*512]  f32
  float* out = (float*)d_out;
  char* ob = (char*)d_out;

  // scratch inside the 64MB quantized region (overwritten by writeout_k)
  unsigned short* zb = (unsigned short*)ob;                  // 33,554,432 B
  unsigned short* eb = (unsigned short*)(ob + 33554432);     //  8,388,608 B
  float* b32   = (float*)(ob + 41943040);                    //     32,768 B
  float* a32   = (float*)(ob + 41975808);                    //    131,072 B
  float* candk = (float*)(ob + 42106880);                    //  8,388,608 B
  int*   candi = (int*)(ob + 50495488);                      //  8,388,608 B

  float* lossp = out + 16777216;
  float* idxs  = out + 16777217;
  double* accum = (double*)d_ws;

  hipMemsetAsync(d_ws, 0, sizeof(double), stream);
  cvtnorm_k<<<8192, 256, 0, stream>>>(z, zb, a32);
  cvtnorm_k<<<2048, 256, 0, stream>>>(e, eb, b32);
  gemm_topk<<<2048, 256, 0, stream>>>(zb, eb, b32, candk, candi);
  rescore_np<<<8192, 256, 0, stream>>>(z, e, a32, b32, candk, candi, idxs);
  writeout_k<<<512, 256, 0, stream>>>(z, e, idxs, out, accum);
  finalize_k<<<1, 1, 0, stream>>>(accum, lossp);
}

// Round 3
// 944.604 us; speedup vs baseline: 1.6161x; 1.1675x over previous
//
#include <hip/hip_runtime.h>

// ---------------------------------------------------------------------------
// VectorQuantizer, np-fp32-faithful argmin. Round 8 = round 7 + M-tile 256:
//   THEORY: FETCH 2.08GB == per-block compulsory (1MB B + 128KB A) * 2048
//   blocks -> zero inter-block L2 reuse; traffic = (K/Nc)|A| + (N/Mr)|B|.
//   Mr 128->256 halves the dominant B term: 2.3GB -> 1.25GB of L2-miss
//   traffic. 512-thread blocks (8 waves, 4x2 grid of 64x64 wave tiles),
//   grid 1024, by=blk&7 XCD pinning preserved, swizzled staging unchanged.
//   - XOR swizzle on LDS K-chunks (slot = chunk ^ (row&7)), source-permuted
//     staging since global_load_lds scatters base + lane*16
//   - round-7 fixes kept: wave-per-row lane-per-candidate rescore (np
//     RN32-chain bit-identical), 1024-block grid-stride writeout
// Scratch inside d_out quantized region (overwritten by writeout_k):
//   [0) zb 32MB][32M) eb 8MB][40M) b32 32KB][+32K) a32 128KB]
//   [+128K) candk 8MB][+8M) candi 8MB]   (ends ~58.9MB < 64MB)
// d_ws: 8 bytes (loss accumulator).
// ---------------------------------------------------------------------------

#define N_ROWS 32768
#define K_CODES 8192
#define DIM 512

typedef __attribute__((ext_vector_type(8))) short short8;
typedef __attribute__((ext_vector_type(4))) float f32x4;

#define MARGIN 5e-4f

__device__ __forceinline__ unsigned short f2bf(float f) {
  unsigned int u = __float_as_uint(f);
  u = u + 0x7fffu + ((u >> 16) & 1u);   // round-to-nearest-even
  return (unsigned short)(u >> 16);
}

__device__ __forceinline__ double shfl_xor_dbl(double v, int m) {
  union { double d; int i[2]; } u;
  u.d = v;
  u.i[0] = __shfl_xor(u.i[0], m, 64);
  u.i[1] = __shfl_xor(u.i[1], m, 64);
  return u.d;
}

// opaque: block fp contraction across this value (keep separate RN32 steps)
__device__ __forceinline__ float opaque_f(float x) {
  asm volatile("" : "+v"(x));
  return x;
}

// ------- 1) fused fp32 -> bf16 + row squared-norm (one wave per row) -------
__global__ __launch_bounds__(256) void cvtnorm_k(const float* __restrict__ in,
                                                 unsigned short* __restrict__ outb,
                                                 float* __restrict__ outn) {
  const int r = blockIdx.x * 4 + (threadIdx.x >> 6);
  const int lane = threadIdx.x & 63;
  const float* xr = in + (size_t)r * DIM + lane * 8;
  const float4 a = *(const float4*)xr;
  const float4 b = *(const float4*)(xr + 4);
  uint4 o;
  o.x = (unsigned)f2bf(a.x) | ((unsigned)f2bf(a.y) << 16);
  o.y = (unsigned)f2bf(a.z) | ((unsigned)f2bf(a.w) << 16);
  o.z = (unsigned)f2bf(b.x) | ((unsigned)f2bf(b.y) << 16);
  o.w = (unsigned)f2bf(b.z) | ((unsigned)f2bf(b.w) << 16);
  *(uint4*)(outb + (size_t)r * DIM + lane * 8) = o;
  double s = (double)a.x * a.x + (double)a.y * a.y + (double)a.z * a.z + (double)a.w * a.w
           + (double)b.x * b.x + (double)b.y * b.y + (double)b.z * b.z + (double)b.w * b.w;
#pragma unroll
  for (int m = 1; m < 64; m <<= 1) s += shfl_xor_dbl(s, m);
  if (lane == 0) outn[r] = (float)s;
}

// ---------------- 2) bf16 GEMM + fused streamed top-4 ----------------------
// grid 1024: bx=blk>>3 -> 256 z-rows; by=blk&7 -> 1024-code chunk (ct<8).
// Block 512 = 8 waves 4x2; wave tile 64x64 = 4x4 MFMA 16x16x32.
// LDS bank-conflict fix: K-chunk c (16B) of row r lives at slot (c ^ (r&7)).
// LDS map: A staging [0,32K), B staging [32K,48K); scorebuf [256][67] f32
// aliases staging (used only after kt loop, fenced by barriers); e2s at 68608.
__global__ __launch_bounds__(512, 4) void gemm_topk(
    const unsigned short* __restrict__ A,   // z bf16 [32768][512]
    const unsigned short* __restrict__ B,   // e bf16 [8192][512]
    const float* __restrict__ en2,          // [8192] = b32
    float* __restrict__ candk,              // [32768][64]
    int* __restrict__ candi)                // [32768][64]
{
  __shared__ char lds[69120];
  float* scorebuf = (float*)lds;                 // [256][67], aliases staging
  float* e2s = (float*)(lds + 68608);            // [128]

  const int tid = threadIdx.x;
  const int lane = tid & 63, wave = tid >> 6;    // wave 0..7
  const int wm = wave >> 1, wn = wave & 1;       // 4x2 wave grid
  const int quad = lane >> 4, lcol = lane & 15;
  const int bx = blockIdx.x >> 3, by = blockIdx.x & 7;
  const int row0 = bx * 256;
  const int cstart = by * 1024;                  // FULL coverage: 8 x 1024
  const int hf = tid & 1, srow = tid >> 1;       // scan ownership (srow 0..255)

  float tk0 = 3.4e38f, tk1 = 3.4e38f, tk2 = 3.4e38f, tk3 = 3.4e38f;
  int ti0 = 0, ti1 = 0, ti2 = 0, ti3 = 0;

  // staging: lane -> (local row, swizzled source chunk)
  const int srw = lane >> 3;                     // 0..7
  const int sch = (lane & 7) ^ srw;              // source K-chunk (16B units)
  const unsigned short* Ag =
      A + ((size_t)(row0 + wave * 32 + srw)) * DIM + sch * 8;   // 8 waves x 32 rows
  const int ldsA = wave * 4096;                  // [0, 32K)
  const int ldsB = 32768 + wave * 2048;          // [32K, 48K), 8 waves x 16 rows

  // fragment readers: row byte base + swizzled chunk offset
  const int xr = lcol & 7;
  int abase[4], bbase[4];
#pragma unroll
  for (int i = 0; i < 4; ++i) abase[i] = (wm * 64 + i * 16 + lcol) * 128;
#pragma unroll
  for (int j = 0; j < 4; ++j) bbase[j] = 32768 + (wn * 64 + j * 16 + lcol) * 128;
  int coff[2];
#pragma unroll
  for (int kk = 0; kk < 2; ++kk) coff[kk] = ((kk * 4 + quad) ^ xr) * 16;

#pragma unroll 1
  for (int ct = 0; ct < 8; ++ct) {
    const int c0 = cstart + ct * 128;
    if (tid < 128) e2s[tid] = en2[c0 + tid];
    const unsigned short* Bg =
        B + ((size_t)(c0 + wave * 16 + srw)) * DIM + sch * 8;

    f32x4 acc[4][4];
#pragma unroll
    for (int i = 0; i < 4; ++i)
#pragma unroll
      for (int j = 0; j < 4; ++j) acc[i][j] = 0.f;

#pragma unroll
    for (int kt = 0; kt < 8; ++kt) {
      const int k0 = kt * 64;
      __syncthreads();
#pragma unroll
      for (int j = 0; j < 4; ++j) {
        __builtin_amdgcn_global_load_lds(
            (const __attribute__((address_space(1))) void*)(uintptr_t)(Ag + k0 + j * (8 * DIM)),
            (__attribute__((address_space(3))) void*)(uintptr_t)(lds + ldsA + j * 1024),
            16, 0, 0);
      }
#pragma unroll
      for (int j = 0; j < 2; ++j) {
        __builtin_amdgcn_global_load_lds(
            (const __attribute__((address_space(1))) void*)(uintptr_t)(Bg + k0 + j * (8 * DIM)),
            (__attribute__((address_space(3))) void*)(uintptr_t)(lds + ldsB + j * 1024),
            16, 0, 0);
      }
      __syncthreads();
#pragma unroll
      for (int kk = 0; kk < 2; ++kk) {
        short8 af[4], bfr[4];
#pragma unroll
        for (int i = 0; i < 4; ++i) af[i] = *(const short8*)(lds + abase[i] + coff[kk]);
#pragma unroll
        for (int j = 0; j < 4; ++j) bfr[j] = *(const short8*)(lds + bbase[j] + coff[kk]);
#pragma unroll
        for (int i = 0; i < 4; ++i)
#pragma unroll
          for (int j = 0; j < 4; ++j)
            acc[i][j] = __builtin_amdgcn_mfma_f32_16x16x32_bf16(af[i], bfr[j], acc[i][j], 0, 0, 0);
      }
    }

#pragma unroll 1
    for (int h = 0; h < 2; ++h) {
      __syncthreads();
      if (wn == h) {
#pragma unroll
        for (int i = 0; i < 4; ++i)
#pragma unroll
          for (int j = 0; j < 4; ++j) {
            const float eb2 = e2s[64 * h + 16 * j + lcol];
#pragma unroll
            for (int r = 0; r < 4; ++r)
              scorebuf[(wm * 64 + i * 16 + quad * 4 + r) * 67 + 16 * j + lcol] =
                  fmaf(acc[i][j][r], -2.0f, eb2);
          }
      }
      __syncthreads();
      const float* sp = scorebuf + srow * 67 + hf * 32;
      const int idbase = c0 + 64 * h + 32 * hf;
#pragma unroll 8
      for (int cc = 0; cc < 32; ++cc) {
        const float key = sp[cc];
        if (key < tk3) {
          const int id = idbase + cc;
          if (key < tk2) {
            tk3 = tk2; ti3 = ti2;
            if (key < tk1) {
              tk2 = tk1; ti2 = ti1;
              if (key < tk0) { tk1 = tk0; ti1 = ti0; tk0 = key; ti0 = id; }
              else           { tk1 = key; ti1 = id; }
            } else { tk2 = key; ti2 = id; }
          } else { tk3 = key; ti3 = id; }
        }
      }
    }
  }

  const size_t cb = ((size_t)(row0 + srow)) * 64 + by * 8 + hf * 4;
  candk[cb + 0] = tk0; candk[cb + 1] = tk1; candk[cb + 2] = tk2; candk[cb + 3] = tk3;
  candi[cb + 0] = ti0; candi[cb + 1] = ti1; candi[cb + 2] = ti2; candi[cb + 3] = ti3;
}

// ---------------- 3) np-faithful fp32 rescore, wave-per-row ----------------
// One wave per row; LANE j owns candidate j (64 in parallel). Per-candidate
// arithmetic bit-identical: OpenBLAS sgemm model m32 = RN32(chain(0..383) +
// chain(384..511)), sequential fp32 fma chains; d = RN32(RN32(a+b)-RN32(2m)).
// Winner = lexicographic min (d, c).
__global__ __launch_bounds__(256) void rescore_np(
    const float* __restrict__ z, const float* __restrict__ e,
    const float* __restrict__ a32, const float* __restrict__ b32,
    const float* __restrict__ candk, const int* __restrict__ candi,
    float* __restrict__ idxout)
{
  const int row = blockIdx.x * 4 + (threadIdx.x >> 6);
  const int lane = threadIdx.x & 63;

  const float myk = candk[(size_t)row * 64 + lane];
  float kmin = myk;
#pragma unroll
  for (int m = 1; m < 64; m <<= 1) kmin = fminf(kmin, __shfl_xor(kmin, m, 64));
  const float cut = kmin + MARGIN;

  float bd = 3.4e38f;
  int bc = 0x7fffffff;
  if (myk <= cut) {
    const int c = candi[(size_t)row * 64 + lane];
    const float* zr = z + (size_t)row * DIM;
    const float* er = e + (size_t)c * DIM;
    // panel A: k = 0..383, sequential fp32 fma chain
    float s = 0.0f;
#pragma unroll 4
    for (int k4 = 0; k4 < 96; ++k4) {
      const float4 zv = *(const float4*)(zr + k4 * 4);
      const float4 ev = *(const float4*)(er + k4 * 4);
      s = fmaf(zv.x, ev.x, s);
      s = fmaf(zv.y, ev.y, s);
      s = fmaf(zv.z, ev.z, s);
      s = fmaf(zv.w, ev.w, s);
    }
    const float cA = s;
    // panel B: k = 384..511
    s = 0.0f;
#pragma unroll 4
    for (int k4 = 96; k4 < 128; ++k4) {
      const float4 zv = *(const float4*)(zr + k4 * 4);
      const float4 ev = *(const float4*)(er + k4 * 4);
      s = fmaf(zv.x, ev.x, s);
      s = fmaf(zv.y, ev.y, s);
      s = fmaf(zv.z, ev.z, s);
      s = fmaf(zv.w, ev.w, s);
    }
    const float m = cA + s;                    // RN32 panel combine
    const float t1 = a32[row] + b32[c];        // RN32(a + b_c)
    const float t2 = opaque_f(2.0f * m);       // RN32(2*m), no contraction
    bd = t1 - t2;                              // RN32(t1 - t2)
    bc = c;
  }
  // lexicographic (d, c) min across the wave
#pragma unroll
  for (int mm = 1; mm < 64; mm <<= 1) {
    const float od = __shfl_xor(bd, mm, 64);
    const int oc = __shfl_xor(bc, mm, 64);
    if (od < bd || (od == bd && oc < bc)) { bd = od; bc = oc; }
  }
  if (lane == 0) idxout[row] = (float)bc;
}

// ---------------- 4) gather + straight-through output + loss ---------------
// Grid-stride over 4,194,304 float4-chunks with 1024 blocks: ONE fp64 atomic
// per block.
__global__ __launch_bounds__(256) void writeout_k(
    const float* __restrict__ z, const float* __restrict__ e,
    const float* __restrict__ idxf, float* __restrict__ outq,
    double* __restrict__ accum)
{
  const int tid = threadIdx.x;
  double s = 0.0;
  size_t gid = (size_t)blockIdx.x * 256 + tid;
#pragma unroll 1
  for (int it = 0; it < 16; ++it, gid += 262144) {
    const int row = (int)(gid >> 7);
    const int dq = ((int)gid & 127) << 2;
    const int c = (int)idxf[row];
    const float4 q4 = *(const float4*)(e + (size_t)c * DIM + dq);
    const float4 z4 = *(const float4*)(z + (size_t)row * DIM + dq);
    const float tx = q4.x - z4.x, ty = q4.y - z4.y, tz = q4.z - z4.z, tw = q4.w - z4.w;
    float4 o;
    o.x = z4.x + tx; o.y = z4.y + ty; o.z = z4.z + tz; o.w = z4.w + tw;
    *(float4*)(outq + (size_t)row * DIM + dq) = o;
    s += (double)tx * tx + (double)ty * ty + (double)tz * tz + (double)tw * tw;
  }
#pragma unroll
  for (int m = 1; m < 64; m <<= 1) s += shfl_xor_dbl(s, m);
  __shared__ double wsum[4];
  if ((tid & 63) == 0) wsum[tid >> 6] = s;
  __syncthreads();
  if (tid == 0) atomicAdd(accum, wsum[0] + wsum[1] + wsum[2] + wsum[3]);
}

// ---------------- 5) finalize loss -----------------------------------------
__global__ void finalize_k(const double* __restrict__ accum, float* __restrict__ lossp) {
  *lossp = (float)(1.25 * accum[0] / (double)((size_t)N_ROWS * DIM));
}

// ---------------------------------------------------------------------------
extern "C" void kernel_launch(void* const* d_in, const int* in_sizes, int n_in,
                              void* d_out, int out_size, void* d_ws, size_t ws_size,
                              hipStream_t stream) {
  const float* z = (const float*)d_in[0];   // [32768*512] f32
  const float* e = (const float*)d_in[1];   // [8192*512]  f32
  float* out = (float*)d_out;
  char* ob = (char*)d_out;

  // scratch inside the 64MB quantized region (overwritten by writeout_k)
  unsigned short* zb = (unsigned short*)ob;                  // 33,554,432 B
  unsigned short* eb = (unsigned short*)(ob + 33554432);     //  8,388,608 B
  float* b32   = (float*)(ob + 41943040);                    //     32,768 B
  float* a32   = (float*)(ob + 41975808);                    //    131,072 B
  float* candk = (float*)(ob + 42106880);                    //  8,388,608 B
  int*   candi = (int*)(ob + 50495488);                      //  8,388,608 B

  float* lossp = out + 16777216;
  float* idxs  = out + 16777217;
  double* accum = (double*)d_ws;

  hipMemsetAsync(d_ws, 0, sizeof(double), stream);
  cvtnorm_k<<<8192, 256, 0, stream>>>(z, zb, a32);
  cvtnorm_k<<<2048, 256, 0, stream>>>(e, eb, b32);
  gemm_topk<<<1024, 512, 0, stream>>>(zb, eb, b32, candk, candi);
  rescore_np<<<8192, 256, 0, stream>>>(z, e, a32, b32, candk, candi, idxs);
  writeout_k<<<1024, 256, 0, stream>>>(z, e, idxs, out, accum);
  finalize_k<<<1, 1, 0, stream>>>(accum, lossp);
}

// Round 5
// 788.165 us; speedup vs baseline: 1.9369x; 1.1985x over previous
//
#include <hip/hip_runtime.h>

// ---------------------------------------------------------------------------
// VectorQuantizer, np-fp32-faithful argmin. Round 10 = round 9 RACE FIX:
//   Round-9 bug: STAGE(kt+1) issued BEFORE the barrier with 2 buffers ->
//   write target == buffer still being ds_read by lagging waves in
//   COMPUTE(kt-1) (cross-wave WAR race; m152). Fix:
//   TRIPLE buffer + issue-AFTER-barrier, counted vmcnt (never 0 in loop):
//     iter kt: vmcnt(3); s_barrier; STAGE(kt+2 -> buf[(kt+2)%3]);
//              COMPUTE(buf[kt%3])
//   - read-ready: in-order vmcnt retirement + barrier => all waves' kt landed
//   - write-safe: buf[(kt+2)%3]==buf[(kt-1)%3]; its readers retired their
//     ds_reads before the iter-kt barrier; STAGE fenced after barrier by
//     asm-"memory" + sched_barrier(0)
//   Steady state 3-6 loads/thread in flight -> latency covered, no drain.
//   BK=32, bufs 3 x 24KB at 0/24576/49152; scorebuf [256][67] aliases staging
//   (only used after drained epilogue); e2sAll [1024] at 73728; LDS 77824
//   -> 2 blocks/CU. Swizzle: slot s of row r holds chunk s ^ ((r>>1)&3),
//   staged via pre-permuted source (rule 21). Accumulation order unchanged.
//   - M-tile 256 kept (round-8: FETCH 2.08->1.63GB, 740->583us)
//   - wave-per-row lane-per-candidate rescore, grid-stride writeout kept
// Scratch inside d_out quantized region (overwritten by writeout_k):
//   [0) zb 32MB][32M) eb 8MB][40M) b32 32KB][+32K) a32 128KB]
//   [+128K) candk 8MB][+8M) candi 8MB]   (ends ~58.9MB < 64MB)
// d_ws: 8 bytes (loss accumulator).
// ---------------------------------------------------------------------------

#define N_ROWS 32768
#define K_CODES 8192
#define DIM 512

typedef __attribute__((ext_vector_type(8))) short short8;
typedef __attribute__((ext_vector_type(4))) float f32x4;

#define MARGIN 5e-4f

__device__ __forceinline__ unsigned short f2bf(float f) {
  unsigned int u = __float_as_uint(f);
  u = u + 0x7fffu + ((u >> 16) & 1u);   // round-to-nearest-even
  return (unsigned short)(u >> 16);
}

__device__ __forceinline__ double shfl_xor_dbl(double v, int m) {
  union { double d; int i[2]; } u;
  u.d = v;
  u.i[0] = __shfl_xor(u.i[0], m, 64);
  u.i[1] = __shfl_xor(u.i[1], m, 64);
  return u.d;
}

// opaque: block fp contraction across this value (keep separate RN32 steps)
__device__ __forceinline__ float opaque_f(float x) {
  asm volatile("" : "+v"(x));
  return x;
}

// ------- 1) fused fp32 -> bf16 + row squared-norm (one wave per row) -------
__global__ __launch_bounds__(256) void cvtnorm_k(const float* __restrict__ in,
                                                 unsigned short* __restrict__ outb,
                                                 float* __restrict__ outn) {
  const int r = blockIdx.x * 4 + (threadIdx.x >> 6);
  const int lane = threadIdx.x & 63;
  const float* xr = in + (size_t)r * DIM + lane * 8;
  const float4 a = *(const float4*)xr;
  const float4 b = *(const float4*)(xr + 4);
  uint4 o;
  o.x = (unsigned)f2bf(a.x) | ((unsigned)f2bf(a.y) << 16);
  o.y = (unsigned)f2bf(a.z) | ((unsigned)f2bf(a.w) << 16);
  o.z = (unsigned)f2bf(b.x) | ((unsigned)f2bf(b.y) << 16);
  o.w = (unsigned)f2bf(b.z) | ((unsigned)f2bf(b.w) << 16);
  *(uint4*)(outb + (size_t)r * DIM + lane * 8) = o;
  double s = (double)a.x * a.x + (double)a.y * a.y + (double)a.z * a.z + (double)a.w * a.w
           + (double)b.x * b.x + (double)b.y * b.y + (double)b.z * b.z + (double)b.w * b.w;
#pragma unroll
  for (int m = 1; m < 64; m <<= 1) s += shfl_xor_dbl(s, m);
  if (lane == 0) outn[r] = (float)s;
}

// ---------------- 2) bf16 GEMM + fused streamed top-4 ----------------------
// grid 1024: bx=blk>>3 -> 256 z-rows; by=blk&7 -> 1024-code chunk (ct<8).
// Block 512 = 8 waves 4x2; wave tile 64x64 = 4x4 MFMA 16x16x32; BK=32.
// Triple-buffered staging (24KB each): 0 / 24576 / 49152.
// scorebuf [256][67] f32 aliases [0,68608) (used only after drained kt loop);
// e2sAll [1024] f32 at 73728. LDS total 77824 -> 2 blocks/CU.
// Swizzle: row r (64B) slot s holds source chunk s ^ ((r>>1)&3).
__global__ __launch_bounds__(512, 4) void gemm_topk(
    const unsigned short* __restrict__ A,   // z bf16 [32768][512]
    const unsigned short* __restrict__ B,   // e bf16 [8192][512]
    const float* __restrict__ en2,          // [8192] = b32
    float* __restrict__ candk,              // [32768][64]
    int* __restrict__ candi)                // [32768][64]
{
  __shared__ char lds[77824];
  float* scorebuf = (float*)lds;                 // [256][67], aliases staging
  float* e2sAll = (float*)(lds + 73728);         // [1024]

  const int tid = threadIdx.x;
  const int lane = tid & 63, wave = tid >> 6;    // wave 0..7
  const int wm = wave >> 1, wn = wave & 1;       // 4x2 wave grid
  const int quad = lane >> 4, lcol = lane & 15;
  const int bx = blockIdx.x >> 3, by = blockIdx.x & 7;
  const int row0 = bx * 256;
  const int cstart = by * 1024;                  // FULL coverage: 8 x 1024
  const int hf = tid & 1, srow = tid >> 1;       // scan ownership (srow 0..255)

  // preload all 1024 e-norms for this chunk (keeps VMEM out of vmcnt count)
  e2sAll[tid] = en2[cstart + tid];
  e2sAll[tid + 512] = en2[cstart + 512 + tid];

  float tk0 = 3.4e38f, tk1 = 3.4e38f, tk2 = 3.4e38f, tk3 = 3.4e38f;
  int ti0 = 0, ti1 = 0, ti2 = 0, ti3 = 0;

  // staging: lane l covers (row = base + (l>>2), lds-slot = l&3); the source
  // chunk is pre-permuted: sch = (l&3) ^ ((l>>3)&3)  [= slot ^ ((row>>1)&3)]
  const int schm = (lane & 3) ^ ((lane >> 3) & 3);
  const unsigned short* Ag =
      A + ((size_t)(row0 + wave * 32 + (lane >> 2))) * DIM + schm * 8;
  const int dstA = wave * 2048;                  // 2 gload_lds: 16 rows each
  const int dstB = 16384 + wave * 1024;          // 16 rows per wave

  // fragment readers: row byte base + swizzled chunk offset
  const int swz = (quad ^ ((lcol >> 1) & 3)) * 16;
  int aoff[4], boff[4];
#pragma unroll
  for (int i = 0; i < 4; ++i) aoff[i] = (wm * 64 + i * 16 + lcol) * 64 + swz;
#pragma unroll
  for (int j = 0; j < 4; ++j) boff[j] = 16384 + (wn * 64 + j * 16 + lcol) * 64 + swz;

#define ASGP const __attribute__((address_space(1))) void*
#define LDSP __attribute__((address_space(3))) void*
#define STAGE(ktv, bb) do {                                                        \
    const unsigned short* As_ = Ag + (ktv) * 32;                                   \
    const unsigned short* Bs_ = Bg + (ktv) * 32;                                   \
    __builtin_amdgcn_global_load_lds((ASGP)(uintptr_t)(As_),                       \
        (LDSP)(uintptr_t)(lds + (bb) + dstA), 16, 0, 0);                           \
    __builtin_amdgcn_global_load_lds((ASGP)(uintptr_t)(As_ + 16 * DIM),            \
        (LDSP)(uintptr_t)(lds + (bb) + dstA + 1024), 16, 0, 0);                    \
    __builtin_amdgcn_global_load_lds((ASGP)(uintptr_t)(Bs_),                       \
        (LDSP)(uintptr_t)(lds + (bb) + dstB), 16, 0, 0);                           \
  } while (0)

#define COMPUTE(cbb) do {                                                          \
    short8 af[4], bv[4];                                                           \
    _Pragma("unroll")                                                              \
    for (int i = 0; i < 4; ++i) af[i] = *(const short8*)(lds + (cbb) + aoff[i]);   \
    _Pragma("unroll")                                                              \
    for (int j = 0; j < 4; ++j) bv[j] = *(const short8*)(lds + (cbb) + boff[j]);   \
    _Pragma("unroll")                                                              \
    for (int i = 0; i < 4; ++i)                                                    \
      _Pragma("unroll")                                                            \
      for (int j = 0; j < 4; ++j)                                                  \
        acc[i][j] = __builtin_amdgcn_mfma_f32_16x16x32_bf16(af[i], bv[j],          \
                                                            acc[i][j], 0, 0, 0);   \
  } while (0)

#pragma unroll 1
  for (int ct = 0; ct < 8; ++ct) {
    const int c0 = cstart + ct * 128;
    const unsigned short* Bg =
        B + ((size_t)(c0 + wave * 16 + (lane >> 2))) * DIM + schm * 8;

    f32x4 acc[4][4];
#pragma unroll
    for (int i = 0; i < 4; ++i)
#pragma unroll
      for (int j = 0; j < 4; ++j) acc[i][j] = 0.f;

    __syncthreads();                 // staging/scorebuf region free (drains all)
    STAGE(0, 0);
    STAGE(1, 24576);
    int cb = 0, nb = 24576, fb = 49152;   // rotating buffer bases
#pragma unroll 1
    for (int kt = 0; kt < 15; ++kt) {
      // own STAGE(kt) landed (in-order retirement; kt+1 may stay in flight)
      asm volatile("s_waitcnt vmcnt(3)" ::: "memory");
      __builtin_amdgcn_s_barrier();          // => ALL waves' STAGE(kt) landed
      asm volatile("" ::: "memory");         // no memory op hoists above barrier
      __builtin_amdgcn_sched_barrier(0);
      // fb == buffer read at COMPUTE(kt-1); its readers retired their ds_reads
      // before arriving at the barrier above -> safe to overwrite now.
      if (kt < 14) STAGE(kt + 2, fb);
      COMPUTE(cb);
      const int t = cb; cb = nb; nb = fb; fb = t;
    }
    asm volatile("s_waitcnt vmcnt(0)" ::: "memory");
    __builtin_amdgcn_s_barrier();
    asm volatile("" ::: "memory");
    __builtin_amdgcn_sched_barrier(0);
    COMPUTE(cb);                     // kt=15 (15%3==0 -> cb cycled back to 0)

#pragma unroll 1
    for (int h = 0; h < 2; ++h) {
      __syncthreads();
      if (wn == h) {
#pragma unroll
        for (int i = 0; i < 4; ++i)
#pragma unroll
          for (int j = 0; j < 4; ++j) {
            const float eb2 = e2sAll[ct * 128 + 64 * h + 16 * j + lcol];
#pragma unroll
            for (int r = 0; r < 4; ++r)
              scorebuf[(wm * 64 + i * 16 + quad * 4 + r) * 67 + 16 * j + lcol] =
                  fmaf(acc[i][j][r], -2.0f, eb2);
          }
      }
      __syncthreads();
      const float* sp = scorebuf + srow * 67 + hf * 32;
      const int idbase = c0 + 64 * h + 32 * hf;
#pragma unroll 8
      for (int cc = 0; cc < 32; ++cc) {
        const float key = sp[cc];
        if (key < tk3) {
          const int id = idbase + cc;
          if (key < tk2) {
            tk3 = tk2; ti3 = ti2;
            if (key < tk1) {
              tk2 = tk1; ti2 = ti1;
              if (key < tk0) { tk1 = tk0; ti1 = ti0; tk0 = key; ti0 = id; }
              else           { tk1 = key; ti1 = id; }
            } else { tk2 = key; ti2 = id; }
          } else { tk3 = key; ti3 = id; }
        }
      }
    }
  }

  const size_t cb2 = ((size_t)(row0 + srow)) * 64 + by * 8 + hf * 4;
  candk[cb2 + 0] = tk0; candk[cb2 + 1] = tk1; candk[cb2 + 2] = tk2; candk[cb2 + 3] = tk3;
  candi[cb2 + 0] = ti0; candi[cb2 + 1] = ti1; candi[cb2 + 2] = ti2; candi[cb2 + 3] = ti3;
}

// ---------------- 3) np-faithful fp32 rescore, wave-per-row ----------------
// One wave per row; LANE j owns candidate j (64 in parallel). Per-candidate
// arithmetic bit-identical: OpenBLAS sgemm model m32 = RN32(chain(0..383) +
// chain(384..511)), sequential fp32 fma chains; d = RN32(RN32(a+b)-RN32(2m)).
// Winner = lexicographic min (d, c).
__global__ __launch_bounds__(256) void rescore_np(
    const float* __restrict__ z, const float* __restrict__ e,
    const float* __restrict__ a32, const float* __restrict__ b32,
    const float* __restrict__ candk, const int* __restrict__ candi,
    float* __restrict__ idxout)
{
  const int row = blockIdx.x * 4 + (threadIdx.x >> 6);
  const int lane = threadIdx.x & 63;

  const float myk = candk[(size_t)row * 64 + lane];
  float kmin = myk;
#pragma unroll
  for (int m = 1; m < 64; m <<= 1) kmin = fminf(kmin, __shfl_xor(kmin, m, 64));
  const float cut = kmin + MARGIN;

  float bd = 3.4e38f;
  int bc = 0x7fffffff;
  if (myk <= cut) {
    const int c = candi[(size_t)row * 64 + lane];
    const float* zr = z + (size_t)row * DIM;
    const float* er = e + (size_t)c * DIM;
    // panel A: k = 0..383, sequential fp32 fma chain
    float s = 0.0f;
#pragma unroll 4
    for (int k4 = 0; k4 < 96; ++k4) {
      const float4 zv = *(const float4*)(zr + k4 * 4);
      const float4 ev = *(const float4*)(er + k4 * 4);
      s = fmaf(zv.x, ev.x, s);
      s = fmaf(zv.y, ev.y, s);
      s = fmaf(zv.z, ev.z, s);
      s = fmaf(zv.w, ev.w, s);
    }
    const float cA = s;
    // panel B: k = 384..511
    s = 0.0f;
#pragma unroll 4
    for (int k4 = 96; k4 < 128; ++k4) {
      const float4 zv = *(const float4*)(zr + k4 * 4);
      const float4 ev = *(const float4*)(er + k4 * 4);
      s = fmaf(zv.x, ev.x, s);
      s = fmaf(zv.y, ev.y, s);
      s = fmaf(zv.z, ev.z, s);
      s = fmaf(zv.w, ev.w, s);
    }
    const float m = cA + s;                    // RN32 panel combine
    const float t1 = a32[row] + b32[c];        // RN32(a + b_c)
    const float t2 = opaque_f(2.0f * m);       // RN32(2*m), no contraction
    bd = t1 - t2;                              // RN32(t1 - t2)
    bc = c;
  }
  // lexicographic (d, c) min across the wave
#pragma unroll
  for (int mm = 1; mm < 64; mm <<= 1) {
    const float od = __shfl_xor(bd, mm, 64);
    const int oc = __shfl_xor(bc, mm, 64);
    if (od < bd || (od == bd && oc < bc)) { bd = od; bc = oc; }
  }
  if (lane == 0) idxout[row] = (float)bc;
}

// ---------------- 4) gather + straight-through output + loss ---------------
// Grid-stride over 4,194,304 float4-chunks with 1024 blocks: ONE fp64 atomic
// per block.
__global__ __launch_bounds__(256) void writeout_k(
    const float* __restrict__ z, const float* __restrict__ e,
    const float* __restrict__ idxf, float* __restrict__ outq,
    double* __restrict__ accum)
{
  const int tid = threadIdx.x;
  double s = 0.0;
  size_t gid = (size_t)blockIdx.x * 256 + tid;
#pragma unroll 1
  for (int it = 0; it < 16; ++it, gid += 262144) {
    const int row = (int)(gid >> 7);
    const int dq = ((int)gid & 127) << 2;
    const int c = (int)idxf[row];
    const float4 q4 = *(const float4*)(e + (size_t)c * DIM + dq);
    const float4 z4 = *(const float4*)(z + (size_t)row * DIM + dq);
    const float tx = q4.x - z4.x, ty = q4.y - z4.y, tz = q4.z - z4.z, tw = q4.w - z4.w;
    float4 o;
    o.x = z4.x + tx; o.y = z4.y + ty; o.z = z4.z + tz; o.w = z4.w + tw;
    *(float4*)(outq + (size_t)row * DIM + dq) = o;
    s += (double)tx * tx + (double)ty * ty + (double)tz * tz + (double)tw * tw;
  }
#pragma unroll
  for (int m = 1; m < 64; m <<= 1) s += shfl_xor_dbl(s, m);
  __shared__ double wsum[4];
  if ((tid & 63) == 0) wsum[tid >> 6] = s;
  __syncthreads();
  if (tid == 0) atomicAdd(accum, wsum[0] + wsum[1] + wsum[2] + wsum[3]);
}

// ---------------- 5) finalize loss -----------------------------------------
__global__ void finalize_k(const double* __restrict__ accum, float* __restrict__ lossp) {
  *lossp = (float)(1.25 * accum[0] / (double)((size_t)N_ROWS * DIM));
}

// ---------------------------------------------------------------------------
extern "C" void kernel_launch(void* const* d_in, const int* in_sizes, int n_in,
                              void* d_out, int out_size, void* d_ws, size_t ws_size,
                              hipStream_t stream) {
  const float* z = (const float*)d_in[0];   // [32768*512] f32
  const float* e = (const float*)d_in[1];   // [8192*512]  f32
  float* out = (float*)d_out;
  char* ob = (char*)d_out;

  // scratch inside the 64MB quantized region (overwritten by writeout_k)
  unsigned short* zb = (unsigned short*)ob;                  // 33,554,432 B
  unsigned short* eb = (unsigned short*)(ob + 33554432);     //  8,388,608 B
  float* b32   = (float*)(ob + 41943040);                    //     32,768 B
  float* a32   = (float*)(ob + 41975808);                    //    131,072 B
  float* candk = (float*)(ob + 42106880);                    //  8,388,608 B
  int*   candi = (int*)(ob + 50495488);                      //  8,388,608 B

  float* lossp = out + 16777216;
  float* idxs  = out + 16777217;
  double* accum = (double*)d_ws;

  hipMemsetAsync(d_ws, 0, sizeof(double), stream);
  cvtnorm_k<<<8192, 256, 0, stream>>>(z, zb, a32);
  cvtnorm_k<<<2048, 256, 0, stream>>>(e, eb, b32);
  gemm_topk<<<1024, 512, 0, stream>>>(zb, eb, b32, candk, candi);
  rescore_np<<<8192, 256, 0, stream>>>(z, e, a32, b32, candk, candi, idxs);
  writeout_k<<<1024, 256, 0, stream>>>(z, e, idxs, out, accum);
  finalize_k<<<1, 1, 0, stream>>>(accum, lossp);
}